// Round 12
// baseline (468.467 us; speedup 1.0000x reference)
//
#include <hip/hip_runtime.h>
#include <math.h>

namespace {
constexpr int kB = 4096;
constexpr int kD = 9216;   // 64*12*12
constexpr int kE = 8;
constexpr int kH = 128;
constexpr int kO = 10;
constexpr int PSTR = 32;   // shorts per h1 pixel (64 B stride)
constexpr int KSPLIT = 8;  // expert GEMM k-split: 9216/8 = 1152

typedef __attribute__((ext_vector_type(8))) short short8;   // 8 bf16
typedef __attribute__((ext_vector_type(4))) float f32x4;    // MFMA acc
typedef __attribute__((ext_vector_type(4))) unsigned u32x4;

typedef const __attribute__((address_space(1))) unsigned GlobU32;
typedef __attribute__((address_space(3))) unsigned LdsU32;

__device__ inline unsigned f2bf(float f) {  // fp32 -> bf16 bits, RNE
  unsigned u = __float_as_uint(f);
  return (u + 0x7fffu + ((u >> 16) & 1u)) >> 16;
}
__device__ inline float bf2f(unsigned b) { return __uint_as_float(b << 16); }

// R14: HW packed bf16 convert (RNE == f2bf on finite values, bit-identical).
__device__ inline unsigned cvtpk(float a, float b) {
  unsigned d;
  asm("v_cvt_pk_bf16_f32 %0, %1, %2" : "=v"(d) : "v"(a), "v"(b));
  return d;
}
__device__ inline void hilo_pair(float a, float b, unsigned& hp, unsigned& lp) {
  hp = cvtpk(a, b);
  float ra = a - __uint_as_float(hp << 16);
  float rb = b - __uint_as_float(hp & 0xffff0000u);
  lp = cvtpk(ra, rb);
}

// w1 -> MFMA B-frag order, bf16 hi/lo. Layout:
// [e][k>>5][nt][lane][j], lane = ((k>>3)&3)<<4 | (n&15), j = k&7.
// Block 0 additionally packs c2w B-frags and zeroes counts+gcur (16 ints).
__global__ __launch_bounds__(256) void prep_w1(
    const float* __restrict__ w1, ushort* __restrict__ w1ph,
    ushort* __restrict__ w1pl, const float* __restrict__ c2w,
    ushort* __restrict__ Bph, ushort* __restrict__ Bpl,
    int* __restrict__ counts) {
  if (blockIdx.x == 0) {
    if (threadIdx.x < 2 * kE) counts[threadIdx.x] = 0;  // counts[0..7]+gcur[8..15]
    for (int i = threadIdx.x; i < 9 * 4 * 64 * 8; i += 256) {
      int j = i & 7, lane = (i >> 3) & 63, nt = (i >> 9) & 3, tap = i >> 11;
      int n = nt * 16 + (lane & 15);
      int c1 = (lane >> 4) * 8 + j;
      float v = c2w[(n * 32 + c1) * 9 + tap];
      unsigned hb = f2bf(v);
      Bph[i] = (ushort)hb;
      Bpl[i] = (ushort)f2bf(v - bf2f(hb));
    }
  }
  int t = blockIdx.x * 256 + threadIdx.x;
  int n = t & 127;
  int rem = t >> 7;
  int k8 = rem % 1152;
  int e = rem / 1152;
  const float* src = w1 + ((size_t)e * kD + (size_t)k8 * 8) * kH + n;
  float v[8];
#pragma unroll
  for (int j = 0; j < 8; ++j) v[j] = src[(size_t)j * kH];
  u32x4 hw, lw;
#pragma unroll
  for (int j = 0; j < 4; ++j) {
    unsigned hp, lp;
    hilo_pair(v[2 * j], v[2 * j + 1], hp, lp);
    hw[j] = hp;
    lw[j] = lp;
  }
  size_t base =
      ((((size_t)e * 288 + (k8 >> 2)) * 8 + (n >> 4)) * 64 +
       (((k8 & 3) << 4) | (n & 15))) * 8;
  *(u32x4*)(w1ph + base) = hw;
  *(u32x4*)(w1pl + base) = lw;
}

// Conv core: R14/R17 state — structural LDS floor (R17 note). R22: gate
// fusion kept (R21: −75 µs net) but moved OUT of the hot mt loop into a
// post-pass coalesced phase. R21's in-loop gw reads were 64 scattered 32-B
// segments per wave-instr (stride 4608 B) inside the MFMA loop (+60 µs);
// now: after the final pass, re-read this block's h row from hb (L2-hot,
// __syncthreads guarantees block-level global visibility) with i=k*256+tid
// -> hb 1KB/instr and gw 2KB/instr fully coalesced, 36 independent iters,
// then the 256->8 LDS tree (dead h1 region) + thread-0 tail. No hval regs
// (rule-#20 scratch risk avoided). Sum order: k-ascending per thread +
// fixed tree — deterministic; same reorder class as R21 (passed).
__global__ __launch_bounds__(256, 2) void conv_kernel(
    const float* __restrict__ x, const float* __restrict__ c1w,
    const float* __restrict__ c1b, const float* __restrict__ b2g,
    const ushort* __restrict__ Bph, const ushort* __restrict__ Bpl,
    const float* __restrict__ gw, float* __restrict__ h,
    int* __restrict__ idx, float* __restrict__ scale,
    int* __restrict__ counts) {
  __shared__ float xs[784];
  __shared__ float w1s[288];
  __shared__ float b1s[32];
  __shared__ ushort h1h[364 * PSTR];  // 23.3 KB
  __shared__ ushort h1l[364 * PSTR];
  const int b = blockIdx.x, tid = threadIdx.x;
  const int lane = tid & 63, wave = tid >> 6;  // wave = ntile (16 chans)

  short8 Bh[9], Bl[9];
#pragma unroll
  for (int tap = 0; tap < 9; ++tap) {
    int fi = ((tap * 4 + wave) * 64 + lane) * 8;
    Bh[tap] = *(const short8*)(Bph + fi);
    Bl[tap] = *(const short8*)(Bpl + fi);
  }
  float b2v = b2g[wave * 16 + (lane & 15)];

  const float* xb = x + (size_t)b * 784;
  for (int i = tid; i < 784; i += 256) xs[i] = xb[i];
  for (int i = tid; i < 288; i += 256) w1s[i] = c1w[i];
  if (tid < 32) b1s[tid] = c1b[tid];
  __syncthreads();

  // Per-thread fixed channel pair; weights + biases hoisted to registers.
  const int cp = (tid & 15) * 2;
  const int pstart = tid >> 4;  // 0..15
  float wreg[18];
#pragma unroll
  for (int j = 0; j < 18; ++j) wreg[j] = w1s[cp * 9 + j];
  const float b0r = b1s[cp], b1r = b1s[cp + 1];

  float* hb = h + (size_t)b * kD;
  for (int pass = 0; pass < 2; ++pass) {
    for (int p = pstart; p < 364; p += 16) {
      int r = p / 26, col = p - r * 26;
      const float* xr = xs + (pass * 12 + r) * 28 + col;
      float v0 = b0r, v1 = b1r;
#pragma unroll
      for (int ky = 0; ky < 3; ++ky)
#pragma unroll
        for (int kx = 0; kx < 3; ++kx) {
          float xv = xr[ky * 28 + kx];
          v0 += xv * wreg[ky * 3 + kx];
          v1 += xv * wreg[9 + ky * 3 + kx];
        }
      v0 = fmaxf(v0, 0.f);
      v1 = fmaxf(v1, 0.f);
      unsigned hp, lp;
      hilo_pair(v0, v1, hp, lp);  // bit-identical to f2bf path (RNE)
      *(unsigned*)&h1h[p * PSTR + cp] = hp;
      *(unsigned*)&h1l[p * PSTR + cp] = lp;
    }
    __syncthreads();
    const int m = lane & 15, kg = lane >> 4;
    for (int mt = 0; mt < 18; ++mt) {
      int cell = mt * 4 + (m >> 2), sub = m & 3;
      int cy = cell / 12, cx = cell - cy * 12;
      int yy = 2 * cy + (sub >> 1), xx = 2 * cx + (sub & 1);
      const ushort* ah = h1h + (yy * 26 + xx) * PSTR + kg * 8;
      const ushort* al = h1l + (yy * 26 + xx) * PSTR + kg * 8;
      f32x4 acc = {0.f, 0.f, 0.f, 0.f};
#pragma unroll
      for (int ky = 0; ky < 3; ++ky)
#pragma unroll
        for (int kx = 0; kx < 3; ++kx) {
          const int tap = ky * 3 + kx;
          short8 Ah = *(const short8*)(ah + (ky * 26 + kx) * PSTR);  // b128
          short8 Al = *(const short8*)(al + (ky * 26 + kx) * PSTR);
          acc = __builtin_amdgcn_mfma_f32_16x16x32_bf16(Al, Bh[tap], acc, 0, 0, 0);
          acc = __builtin_amdgcn_mfma_f32_16x16x32_bf16(Ah, Bl[tap], acc, 0, 0, 0);
          acc = __builtin_amdgcn_mfma_f32_16x16x32_bf16(Ah, Bh[tap], acc, 0, 0, 0);
        }
      int cellg = mt * 4 + kg;
      int gy = cellg / 12, gx = cellg - gy * 12;
      int orow = (pass * 6 + gy) * 12 + gx;
      float p0 = fmaxf(fmaxf(acc[0], acc[1]), fmaxf(acc[2], acc[3]));
      hb[(wave * 16 + m) * 144 + orow] = fmaxf(p0 + b2v, 0.f);
    }
    __syncthreads();
  }

  // ---- fused gate, post-pass, fully parallel + coalesced ----
  {
    float gacc[kE] = {0, 0, 0, 0, 0, 0, 0, 0};
    for (int k = 0; k < kD / 256; ++k) {  // 36 iterations
      const int i = k * 256 + tid;
      const float hv = hb[i];             // L2-hot, 1 KB/instr coalesced
      const float* g = gw + (size_t)i * kE;
      float4 g0 = *(const float4*)g;      // 2 KB/instr coalesced
      float4 g1 = *(const float4*)(g + 4);
      gacc[0] += hv * g0.x;
      gacc[1] += hv * g0.y;
      gacc[2] += hv * g0.z;
      gacc[3] += hv * g0.w;
      gacc[4] += hv * g1.x;
      gacc[5] += hv * g1.y;
      gacc[6] += hv * g1.z;
      gacc[7] += hv * g1.w;
    }
    float* red = (float*)h1h;  // dead h1 region, 256x9 floats (stride-9 pad)
#pragma unroll
    for (int e = 0; e < kE; ++e) red[tid * 9 + e] = gacc[e];
    __syncthreads();
    for (int s = 128; s >= 1; s >>= 1) {
      if (tid < s) {
#pragma unroll
        for (int e = 0; e < kE; ++e)
          red[tid * 9 + e] += red[(tid + s) * 9 + e];
      }
      __syncthreads();
    }
    if (tid == 0) {
      float mx = red[0];
      int bi = 0;
#pragma unroll
      for (int e = 1; e < kE; ++e)
        if (red[e] > mx) { mx = red[e]; bi = e; }
      float s = 0.f;
#pragma unroll
      for (int e = 0; e < kE; ++e) s += expf(red[e] - mx);
      idx[b] = bi;
      scale[b] = 1.0f / s;
      atomicAdd(&counts[bi], 1);
    }
  }
}

// R20: PARALLEL scatter. 16 blocks x 256 tokens: LDS bucket ranks -> one
// global atomicAdd reservation per (block, expert) on gcur (=counts+8,
// zeroed by prep_w1) -> scatter into reserved range. Bucket-internal perm
// order nondeterministic but per-token results are perm-position-invariant.
__global__ __launch_bounds__(256) void scatter_kernel(
    const int* __restrict__ counts, const int* __restrict__ idx,
    int* __restrict__ offsets, int* __restrict__ perm,
    int* __restrict__ gcur) {
  __shared__ int lcnt[kE];
  __shared__ int lbase[kE];
  const int t = threadIdx.x;
  if (t < kE) lcnt[t] = 0;
  __syncthreads();
  const int b = blockIdx.x * 256 + t;
  const int e = idx[b];
  const int lrank = atomicAdd(&lcnt[e], 1);
  __syncthreads();
  if (t < kE) {
    int off = 0;
    for (int q = 0; q < kE; ++q) off += (q < t) ? counts[q] : 0;
    lbase[t] = off + atomicAdd(&gcur[t], lcnt[t]);
    if (blockIdx.x == 0) {
      offsets[t] = off;
      if (t == 0) {
        int tot = 0;
        for (int q = 0; q < kE; ++q) tot += counts[q];
        offsets[kE] = tot;
      }
    }
  }
  __syncthreads();
  perm[lbase[e] + lrank] = b;
}

// MFMA expert GEMM. R18: 128 rows per block as two 64-row halves sharing one
// B-stage per bk (panel re-reads halved). R16: B staged via global_load_lds
// width=16. Numerics bit-identical per token.
__global__ __launch_bounds__(256) void expert_gemm(
    const float* __restrict__ h, const ushort* __restrict__ w1ph,
    const ushort* __restrict__ w1pl, const int* __restrict__ perm,
    const int* __restrict__ offsets, float* __restrict__ preact) {
  const int e = blockIdx.x, ks = blockIdx.y;
  const int start = offsets[e] + blockIdx.z * 128;
  const int end = offsets[e + 1];
  if (start >= end) return;
  const int M = min(128, end - start);
  __shared__ ushort Afh[4096];  // A frags [kstep][g][lane][8], 8 KB
  __shared__ ushort Afl[4096];
  __shared__ ushort Bsh[8192];  // B frags [kstep][nt][lane][8], 16 KB
  __shared__ ushort Bsl[8192];
  __shared__ int rows[128];
  const int tid = threadIdx.x;
  if (tid < 128) rows[tid] = perm[start + min(tid, M - 1)];
  __syncthreads();
  const int wave = tid >> 6, lane = tid & 63;
  const int m15 = lane & 15, kg4 = lane >> 4;
  const int srow = tid >> 2, spart = tid & 3;
  const int kbase = ks * (kD / KSPLIT);
  const float* hpA = h + (size_t)rows[srow] * kD + kbase + spart * 16;
  const float* hpB = h + (size_t)rows[64 + srow] * kD + kbase + spart * 16;
  const int skstep = spart >> 1, skg = (spart & 1) * 2;
  const int sg = srow >> 4, sm = srow & 15;
  ushort* wh0 = &Afh[((skstep * 4 + sg) * 64 + skg * 16 + sm) * 8];
  ushort* wl0 = &Afl[((skstep * 4 + sg) * 64 + skg * 16 + sm) * 8];
  f32x4 acc[2][8];
#pragma unroll
  for (int hf = 0; hf < 2; ++hf)
#pragma unroll
    for (int j = 0; j < 8; ++j) acc[hf][j] = {0.f, 0.f, 0.f, 0.f};

  for (int bk = 0; bk < kD / KSPLIT; bk += 64) {
    // ---- stage B once per bk (async global->LDS), shared by both halves ----
    {
      const size_t bbase =
          ((size_t)e * 288 + ((kbase + bk) >> 5)) * 4096;
#pragma unroll
      for (int q = 0; q < 4; ++q) {
        int c = tid + q * 256;  // b128 chunk id, 1024 total
        __builtin_amdgcn_global_load_lds(
            (GlobU32*)(w1ph + bbase + (size_t)c * 8),
            (LdsU32*)&Bsh[c * 8], 16, 0, 0);
        __builtin_amdgcn_global_load_lds(
            (GlobU32*)(w1pl + bbase + (size_t)c * 8),
            (LdsU32*)&Bsl[c * 8], 16, 0, 0);
      }
    }
#pragma unroll
    for (int hf = 0; hf < 2; ++hf) {
      const float* hp0 = hf ? hpB : hpA;
      // ---- stage A half (cvt_pk hi/lo, bit-identical to f2bf path) ----
#pragma unroll
      for (int c = 0; c < 2; ++c) {
        float4 v0 = *(const float4*)(hp0 + bk + c * 8);
        float4 v1 = *(const float4*)(hp0 + bk + c * 8 + 4);
        float f[8] = {v0.x, v0.y, v0.z, v0.w, v1.x, v1.y, v1.z, v1.w};
        u32x4 hw, lw;
#pragma unroll
        for (int j = 0; j < 4; ++j) {
          unsigned hp, lp;
          hilo_pair(f[2 * j], f[2 * j + 1], hp, lp);
          hw[j] = hp;
          lw[j] = lp;
        }
        *(u32x4*)(wh0 + c * 128) = hw;
        *(u32x4*)(wl0 + c * 128) = lw;
      }
      __syncthreads();  // A ready; (hf==0) also drains B gload_lds vmcnt
#pragma unroll
      for (int kstep = 0; kstep < 2; ++kstep) {
        const ushort* af = &Afh[((kstep * 4 + wave) * 64 + lane) * 8];
        short8 ah = *(const short8*)af;
        short8 al = *(const short8*)(af + (Afl - Afh));
        const ushort* bph = &Bsh[kstep * 4096 + lane * 8];
        const ushort* bpl = &Bsl[kstep * 4096 + lane * 8];
#pragma unroll
        for (int nt = 0; nt < 8; ++nt) {
          short8 bh = *(const short8*)(bph + nt * 512);
          short8 bl = *(const short8*)(bpl + nt * 512);
          acc[hf][nt] = __builtin_amdgcn_mfma_f32_16x16x32_bf16(al, bh, acc[hf][nt], 0, 0, 0);
          acc[hf][nt] = __builtin_amdgcn_mfma_f32_16x16x32_bf16(ah, bl, acc[hf][nt], 0, 0, 0);
          acc[hf][nt] = __builtin_amdgcn_mfma_f32_16x16x32_bf16(ah, bh, acc[hf][nt], 0, 0, 0);
        }
      }
      __syncthreads();  // allow A overwrite (hf=0) / next-bk B overwrite (hf=1)
    }
  }
  float* pb = preact + (size_t)ks * kB * kH;
#pragma unroll
  for (int hf = 0; hf < 2; ++hf)
#pragma unroll
    for (int r = 0; r < 4; ++r) {
      int row = hf * 64 + wave * 16 + kg4 * 4 + r;
      if (row < M) {
        float* pr = pb + (size_t)rows[row] * kH + m15;
#pragma unroll
        for (int nt = 0; nt < 8; ++nt) pr[nt * 16] = acc[hf][nt][r];
      }
    }
}

// Per-token tail. R20: 4 tokens per 256-thread block (one wave per token,
// body verbatim -> bit-identical); 4096 -> 1024 blocks cuts launch/drain.
__global__ __launch_bounds__(256) void expert_tail(
    const float* __restrict__ preact, const float* __restrict__ b1,
    const float* __restrict__ w2, const float* __restrict__ b2,
    const int* __restrict__ idx, const float* __restrict__ scale,
    float* __restrict__ out) {
  const int b = blockIdx.x * 4 + (threadIdx.x >> 6);
  const int lane = threadIdx.x & 63;
  const int e = idx[b];
  float pa = 0.f, pc = 0.f;
#pragma unroll
  for (int ks = 0; ks < KSPLIT; ++ks) {
    const float* ps = preact + ((size_t)ks * kB + b) * kH;
    pa += ps[lane];
    pc += ps[64 + lane];
  }
  float hea = fmaxf(pa + b1[e * kH + lane], 0.f);
  float heb = fmaxf(pc + b1[e * kH + 64 + lane], 0.f);
  const float* w2a = w2 + ((size_t)e * kH + lane) * kO;
  const float* w2b = w2a + 64 * kO;
  float part[kO];
#pragma unroll
  for (int o = 0; o < kO; ++o) part[o] = hea * w2a[o] + heb * w2b[o];
#pragma unroll
  for (int off = 32; off > 0; off >>= 1)
#pragma unroll
    for (int o = 0; o < kO; ++o) part[o] += __shfl_down(part[o], off, 64);
  if (lane == 0) {
    const float sc = scale[b];
    float v[kO], m = -1e30f;
#pragma unroll
    for (int o = 0; o < kO; ++o) {
      v[o] = (part[o] + b2[e * kO + o]) * sc;
      m = fmaxf(m, v[o]);
    }
    float s = 0.f;
#pragma unroll
    for (int o = 0; o < kO; ++o) s += expf(v[o] - m);
    const float lse = m + logf(s);
#pragma unroll
    for (int o = 0; o < kO; ++o) out[(size_t)b * kO + o] = v[o] - lse;
  }
}

}  // namespace

extern "C" void kernel_launch(void* const* d_in, const int* in_sizes, int n_in,
                              void* d_out, int out_size, void* d_ws,
                              size_t ws_size, hipStream_t stream) {
  (void)in_sizes; (void)n_in; (void)out_size; (void)ws_size;
  const float* x   = (const float*)d_in[0];
  const float* c1w = (const float*)d_in[1];
  const float* c1b = (const float*)d_in[2];
  const float* c2w = (const float*)d_in[3];
  const float* c2b = (const float*)d_in[4];
  const float* gw  = (const float*)d_in[5];
  const float* w1  = (const float*)d_in[6];
  const float* b1  = (const float*)d_in[7];
  const float* w2  = (const float*)d_in[8];
  const float* b2  = (const float*)d_in[9];
  float* out = (float*)d_out;

  char* ws = (char*)d_ws;
  float* h = (float*)ws;
  size_t off = (size_t)kB * kD * sizeof(float);                     // 151.0 MB
  ushort* w1ph = (ushort*)(ws + off); off += (size_t)kE * kD * kH * 2;  // 18.9 MB
  ushort* w1pl = (ushort*)(ws + off); off += (size_t)kE * kD * kH * 2;  // 18.9 MB
  float* preact = (float*)(ws + off); off += (size_t)KSPLIT * kB * kH * 4;  // 16.8 MB
  ushort* Bph = (ushort*)(ws + off);  off += 9 * 4 * 64 * 8 * 2;
  ushort* Bpl = (ushort*)(ws + off);  off += 9 * 4 * 64 * 8 * 2;
  int* idx = (int*)(ws + off);        off += (size_t)kB * 4;
  float* scale = (float*)(ws + off);  off += (size_t)kB * 4;
  int* perm = (int*)(ws + off);       off += (size_t)kB * 4;
  int* counts = (int*)(ws + off);     off += 64;   // [0..7]=counts, [8..15]=gcur
  int* offsets = (int*)(ws + off);    off += 64;

  prep_w1<<<4608, 256, 0, stream>>>(w1, w1ph, w1pl, c2w, Bph, Bpl, counts);
  conv_kernel<<<kB, 256, 0, stream>>>(x, c1w, c1b, c2b, Bph, Bpl, gw, h,
                                      idx, scale, counts);
  scatter_kernel<<<kB / 256, 256, 0, stream>>>(counts, idx, offsets, perm,
                                               counts + kE);
  dim3 eg(kE, KSPLIT, 8);
  expert_gemm<<<eg, 256, 0, stream>>>(h, w1ph, w1pl, perm, offsets, preact);
  expert_tail<<<kB / 4, 256, 0, stream>>>(preact, b1, w2, b2, idx, scale, out);
}

// Round 13
// 448.258 us; speedup vs baseline: 1.0451x; 1.0451x over previous
//
#include <hip/hip_runtime.h>
#include <math.h>

namespace {
constexpr int kB = 4096;
constexpr int kD = 9216;   // 64*12*12
constexpr int kE = 8;
constexpr int kH = 128;
constexpr int kO = 10;
constexpr int PSTR = 32;   // shorts per h1 pixel (64 B stride)
constexpr int KSPLIT = 8;  // expert GEMM k-split: 9216/8 = 1152

typedef __attribute__((ext_vector_type(8))) short short8;   // 8 bf16
typedef __attribute__((ext_vector_type(4))) float f32x4;    // MFMA acc
typedef __attribute__((ext_vector_type(4))) unsigned u32x4;

typedef const __attribute__((address_space(1))) unsigned GlobU32;
typedef __attribute__((address_space(3))) unsigned LdsU32;

__device__ inline unsigned f2bf(float f) {  // fp32 -> bf16 bits, RNE
  unsigned u = __float_as_uint(f);
  return (u + 0x7fffu + ((u >> 16) & 1u)) >> 16;
}
__device__ inline float bf2f(unsigned b) { return __uint_as_float(b << 16); }

// R14: HW packed bf16 convert (RNE == f2bf on finite values, bit-identical).
__device__ inline unsigned cvtpk(float a, float b) {
  unsigned d;
  asm("v_cvt_pk_bf16_f32 %0, %1, %2" : "=v"(d) : "v"(a), "v"(b));
  return d;
}
__device__ inline void hilo_pair(float a, float b, unsigned& hp, unsigned& lp) {
  hp = cvtpk(a, b);
  float ra = a - __uint_as_float(hp << 16);
  float rb = b - __uint_as_float(hp & 0xffff0000u);
  lp = cvtpk(ra, rb);
}

// w1 -> MFMA B-frag order, bf16 hi/lo. Layout:
// [e][k>>5][nt][lane][j], lane = ((k>>3)&3)<<4 | (n&15), j = k&7.
// Block 0 additionally packs c2w B-frags and zeroes counts+gcur (16 ints).
__global__ __launch_bounds__(256) void prep_w1(
    const float* __restrict__ w1, ushort* __restrict__ w1ph,
    ushort* __restrict__ w1pl, const float* __restrict__ c2w,
    ushort* __restrict__ Bph, ushort* __restrict__ Bpl,
    int* __restrict__ counts) {
  if (blockIdx.x == 0) {
    if (threadIdx.x < 2 * kE) counts[threadIdx.x] = 0;  // counts[0..7]+gcur[8..15]
    for (int i = threadIdx.x; i < 9 * 4 * 64 * 8; i += 256) {
      int j = i & 7, lane = (i >> 3) & 63, nt = (i >> 9) & 3, tap = i >> 11;
      int n = nt * 16 + (lane & 15);
      int c1 = (lane >> 4) * 8 + j;
      float v = c2w[(n * 32 + c1) * 9 + tap];
      unsigned hb = f2bf(v);
      Bph[i] = (ushort)hb;
      Bpl[i] = (ushort)f2bf(v - bf2f(hb));
    }
  }
  int t = blockIdx.x * 256 + threadIdx.x;
  int n = t & 127;
  int rem = t >> 7;
  int k8 = rem % 1152;
  int e = rem / 1152;
  const float* src = w1 + ((size_t)e * kD + (size_t)k8 * 8) * kH + n;
  float v[8];
#pragma unroll
  for (int j = 0; j < 8; ++j) v[j] = src[(size_t)j * kH];
  u32x4 hw, lw;
#pragma unroll
  for (int j = 0; j < 4; ++j) {
    unsigned hp, lp;
    hilo_pair(v[2 * j], v[2 * j + 1], hp, lp);
    hw[j] = hp;
    lw[j] = lp;
  }
  size_t base =
      ((((size_t)e * 288 + (k8 >> 2)) * 8 + (n >> 4)) * 64 +
       (((k8 & 3) << 4) | (n & 15))) * 8;
  *(u32x4*)(w1ph + base) = hw;
  *(u32x4*)(w1pl + base) = lw;
}

// Conv core: R14/R17 state — structural LDS floor (R17 note). R23: fused
// gate, post-pass, parallel, sourced from LDS. History: R19 (serial wave-0
// gate from LDS) = occupancy collapse; R21 (inline scattered gw in hot
// loop) = 457 µs best; R22 (post-pass from GLOBAL hb) = +72 MB FETCH, the
// block's own h row is half-evicted from the 4 MB/XCD L2 (18 MB live rows
// per XCD). R23 combines the validated pieces: hval[2][18] register carry
// (R19: VGPR 76, no scratch), post-final-pass dump to LDS hrow[9216] (36 KB
// in the 46.6 KB dead h1 union), then R22's full-256-thread gate loop with
// hv from LDS (stride-1, conflict-free) and gw coalesced from L2 (294 KB,
// read-only, L2-resident). Gate numerics BIT-IDENTICAL to R22 (passed):
// same k-ascending per-thread order, same tree, same input bits.
__global__ __launch_bounds__(256, 2) void conv_kernel(
    const float* __restrict__ x, const float* __restrict__ c1w,
    const float* __restrict__ c1b, const float* __restrict__ b2g,
    const ushort* __restrict__ Bph, const ushort* __restrict__ Bpl,
    const float* __restrict__ gw, float* __restrict__ h,
    int* __restrict__ idx, float* __restrict__ scale,
    int* __restrict__ counts) {
  __shared__ float xs[784];
  __shared__ float w1s[288];
  __shared__ float b1s[32];
  __shared__ ushort h1buf[2][364 * PSTR];  // union: h1h/h1l, later hrow+red
  ushort* h1h = &h1buf[0][0];
  ushort* h1l = &h1buf[1][0];
  const int b = blockIdx.x, tid = threadIdx.x;
  const int lane = tid & 63, wave = tid >> 6;  // wave = ntile (16 chans)

  short8 Bh[9], Bl[9];
#pragma unroll
  for (int tap = 0; tap < 9; ++tap) {
    int fi = ((tap * 4 + wave) * 64 + lane) * 8;
    Bh[tap] = *(const short8*)(Bph + fi);
    Bl[tap] = *(const short8*)(Bpl + fi);
  }
  float b2v = b2g[wave * 16 + (lane & 15)];

  const float* xb = x + (size_t)b * 784;
  for (int i = tid; i < 784; i += 256) xs[i] = xb[i];
  for (int i = tid; i < 288; i += 256) w1s[i] = c1w[i];
  if (tid < 32) b1s[tid] = c1b[tid];
  __syncthreads();

  // Per-thread fixed channel pair; weights + biases hoisted to registers.
  const int cp = (tid & 15) * 2;
  const int pstart = tid >> 4;  // 0..15
  float wreg[18];
#pragma unroll
  for (int j = 0; j < 18; ++j) wreg[j] = w1s[cp * 9 + j];
  const float b0r = b1s[cp], b1r = b1s[cp + 1];

  float hval[2][18];  // this thread's 36 h outputs (for the fused gate)
  float* hb = h + (size_t)b * kD;
  for (int pass = 0; pass < 2; ++pass) {
    for (int p = pstart; p < 364; p += 16) {
      int r = p / 26, col = p - r * 26;
      const float* xr = xs + (pass * 12 + r) * 28 + col;
      float v0 = b0r, v1 = b1r;
#pragma unroll
      for (int ky = 0; ky < 3; ++ky)
#pragma unroll
        for (int kx = 0; kx < 3; ++kx) {
          float xv = xr[ky * 28 + kx];
          v0 += xv * wreg[ky * 3 + kx];
          v1 += xv * wreg[9 + ky * 3 + kx];
        }
      v0 = fmaxf(v0, 0.f);
      v1 = fmaxf(v1, 0.f);
      unsigned hp, lp;
      hilo_pair(v0, v1, hp, lp);  // bit-identical to f2bf path (RNE)
      *(unsigned*)&h1h[p * PSTR + cp] = hp;
      *(unsigned*)&h1l[p * PSTR + cp] = lp;
    }
    __syncthreads();
    const int m = lane & 15, kg = lane >> 4;
    for (int mt = 0; mt < 18; ++mt) {
      int cell = mt * 4 + (m >> 2), sub = m & 3;
      int cy = cell / 12, cx = cell - cy * 12;
      int yy = 2 * cy + (sub >> 1), xx = 2 * cx + (sub & 1);
      const ushort* ah = h1h + (yy * 26 + xx) * PSTR + kg * 8;
      const ushort* al = h1l + (yy * 26 + xx) * PSTR + kg * 8;
      f32x4 acc = {0.f, 0.f, 0.f, 0.f};
#pragma unroll
      for (int ky = 0; ky < 3; ++ky)
#pragma unroll
        for (int kx = 0; kx < 3; ++kx) {
          const int tap = ky * 3 + kx;
          short8 Ah = *(const short8*)(ah + (ky * 26 + kx) * PSTR);  // b128
          short8 Al = *(const short8*)(al + (ky * 26 + kx) * PSTR);
          acc = __builtin_amdgcn_mfma_f32_16x16x32_bf16(Al, Bh[tap], acc, 0, 0, 0);
          acc = __builtin_amdgcn_mfma_f32_16x16x32_bf16(Ah, Bl[tap], acc, 0, 0, 0);
          acc = __builtin_amdgcn_mfma_f32_16x16x32_bf16(Ah, Bh[tap], acc, 0, 0, 0);
        }
      int cellg = mt * 4 + kg;
      int gy = cellg / 12, gx = cellg - gy * 12;
      int orow = (pass * 6 + gy) * 12 + gx;
      float p0 = fmaxf(fmaxf(acc[0], acc[1]), fmaxf(acc[2], acc[3]));
      float hv = fmaxf(p0 + b2v, 0.f);
      hb[(wave * 16 + m) * 144 + orow] = hv;
      hval[pass][mt] = hv;
    }
    __syncthreads();
  }

  // ---- fused gate: h1 dead; hrow[9216] + red[2304] in the 11648-float union
  {
    float* hrow = (float*)h1buf;
    const int m = lane & 15, kg = lane >> 4;
#pragma unroll
    for (int pass = 0; pass < 2; ++pass)
#pragma unroll
      for (int mt = 0; mt < 18; ++mt) {
        int cellg = mt * 4 + kg;
        int gy = cellg / 12, gx = cellg - gy * 12;
        int orow = (pass * 6 + gy) * 12 + gx;
        hrow[(wave * 16 + m) * 144 + orow] = hval[pass][mt];
      }
    __syncthreads();
    float gacc[kE] = {0, 0, 0, 0, 0, 0, 0, 0};
    for (int k = 0; k < kD / 256; ++k) {  // 36 iterations
      const int i = k * 256 + tid;
      const float hv = hrow[i];           // LDS, stride-1, conflict-free
      const float* g = gw + (size_t)i * kE;
      float4 g0 = *(const float4*)g;      // 2 KB/instr coalesced, L2-resident
      float4 g1 = *(const float4*)(g + 4);
      gacc[0] += hv * g0.x;
      gacc[1] += hv * g0.y;
      gacc[2] += hv * g0.z;
      gacc[3] += hv * g0.w;
      gacc[4] += hv * g1.x;
      gacc[5] += hv * g1.y;
      gacc[6] += hv * g1.z;
      gacc[7] += hv * g1.w;
    }
    float* red = hrow + kD;  // floats [9216, 11520) of the 11648 available
#pragma unroll
    for (int e = 0; e < kE; ++e) red[tid * 9 + e] = gacc[e];
    __syncthreads();
    for (int s = 128; s >= 1; s >>= 1) {
      if (tid < s) {
#pragma unroll
        for (int e = 0; e < kE; ++e)
          red[tid * 9 + e] += red[(tid + s) * 9 + e];
      }
      __syncthreads();
    }
    if (tid == 0) {
      float mx = red[0];
      int bi = 0;
#pragma unroll
      for (int e = 1; e < kE; ++e)
        if (red[e] > mx) { mx = red[e]; bi = e; }
      float s = 0.f;
#pragma unroll
      for (int e = 0; e < kE; ++e) s += expf(red[e] - mx);
      idx[b] = bi;
      scale[b] = 1.0f / s;
      atomicAdd(&counts[bi], 1);
    }
  }
}

// R20: PARALLEL scatter. 16 blocks x 256 tokens: LDS bucket ranks -> one
// global atomicAdd reservation per (block, expert) on gcur (=counts+8,
// zeroed by prep_w1) -> scatter into reserved range. Bucket-internal perm
// order nondeterministic but per-token results are perm-position-invariant.
__global__ __launch_bounds__(256) void scatter_kernel(
    const int* __restrict__ counts, const int* __restrict__ idx,
    int* __restrict__ offsets, int* __restrict__ perm,
    int* __restrict__ gcur) {
  __shared__ int lcnt[kE];
  __shared__ int lbase[kE];
  const int t = threadIdx.x;
  if (t < kE) lcnt[t] = 0;
  __syncthreads();
  const int b = blockIdx.x * 256 + t;
  const int e = idx[b];
  const int lrank = atomicAdd(&lcnt[e], 1);
  __syncthreads();
  if (t < kE) {
    int off = 0;
    for (int q = 0; q < kE; ++q) off += (q < t) ? counts[q] : 0;
    lbase[t] = off + atomicAdd(&gcur[t], lcnt[t]);
    if (blockIdx.x == 0) {
      offsets[t] = off;
      if (t == 0) {
        int tot = 0;
        for (int q = 0; q < kE; ++q) tot += counts[q];
        offsets[kE] = tot;
      }
    }
  }
  __syncthreads();
  perm[lbase[e] + lrank] = b;
}

// MFMA expert GEMM. R18: 128 rows per block as two 64-row halves sharing one
// B-stage per bk (panel re-reads halved). R16: B staged via global_load_lds
// width=16. Numerics bit-identical per token.
__global__ __launch_bounds__(256) void expert_gemm(
    const float* __restrict__ h, const ushort* __restrict__ w1ph,
    const ushort* __restrict__ w1pl, const int* __restrict__ perm,
    const int* __restrict__ offsets, float* __restrict__ preact) {
  const int e = blockIdx.x, ks = blockIdx.y;
  const int start = offsets[e] + blockIdx.z * 128;
  const int end = offsets[e + 1];
  if (start >= end) return;
  const int M = min(128, end - start);
  __shared__ ushort Afh[4096];  // A frags [kstep][g][lane][8], 8 KB
  __shared__ ushort Afl[4096];
  __shared__ ushort Bsh[8192];  // B frags [kstep][nt][lane][8], 16 KB
  __shared__ ushort Bsl[8192];
  __shared__ int rows[128];
  const int tid = threadIdx.x;
  if (tid < 128) rows[tid] = perm[start + min(tid, M - 1)];
  __syncthreads();
  const int wave = tid >> 6, lane = tid & 63;
  const int m15 = lane & 15, kg4 = lane >> 4;
  const int srow = tid >> 2, spart = tid & 3;
  const int kbase = ks * (kD / KSPLIT);
  const float* hpA = h + (size_t)rows[srow] * kD + kbase + spart * 16;
  const float* hpB = h + (size_t)rows[64 + srow] * kD + kbase + spart * 16;
  const int skstep = spart >> 1, skg = (spart & 1) * 2;
  const int sg = srow >> 4, sm = srow & 15;
  ushort* wh0 = &Afh[((skstep * 4 + sg) * 64 + skg * 16 + sm) * 8];
  ushort* wl0 = &Afl[((skstep * 4 + sg) * 64 + skg * 16 + sm) * 8];
  f32x4 acc[2][8];
#pragma unroll
  for (int hf = 0; hf < 2; ++hf)
#pragma unroll
    for (int j = 0; j < 8; ++j) acc[hf][j] = {0.f, 0.f, 0.f, 0.f};

  for (int bk = 0; bk < kD / KSPLIT; bk += 64) {
    // ---- stage B once per bk (async global->LDS), shared by both halves ----
    {
      const size_t bbase =
          ((size_t)e * 288 + ((kbase + bk) >> 5)) * 4096;
#pragma unroll
      for (int q = 0; q < 4; ++q) {
        int c = tid + q * 256;  // b128 chunk id, 1024 total
        __builtin_amdgcn_global_load_lds(
            (GlobU32*)(w1ph + bbase + (size_t)c * 8),
            (LdsU32*)&Bsh[c * 8], 16, 0, 0);
        __builtin_amdgcn_global_load_lds(
            (GlobU32*)(w1pl + bbase + (size_t)c * 8),
            (LdsU32*)&Bsl[c * 8], 16, 0, 0);
      }
    }
#pragma unroll
    for (int hf = 0; hf < 2; ++hf) {
      const float* hp0 = hf ? hpB : hpA;
      // ---- stage A half (cvt_pk hi/lo, bit-identical to f2bf path) ----
#pragma unroll
      for (int c = 0; c < 2; ++c) {
        float4 v0 = *(const float4*)(hp0 + bk + c * 8);
        float4 v1 = *(const float4*)(hp0 + bk + c * 8 + 4);
        float f[8] = {v0.x, v0.y, v0.z, v0.w, v1.x, v1.y, v1.z, v1.w};
        u32x4 hw, lw;
#pragma unroll
        for (int j = 0; j < 4; ++j) {
          unsigned hp, lp;
          hilo_pair(f[2 * j], f[2 * j + 1], hp, lp);
          hw[j] = hp;
          lw[j] = lp;
        }
        *(u32x4*)(wh0 + c * 128) = hw;
        *(u32x4*)(wl0 + c * 128) = lw;
      }
      __syncthreads();  // A ready; (hf==0) also drains B gload_lds vmcnt
#pragma unroll
      for (int kstep = 0; kstep < 2; ++kstep) {
        const ushort* af = &Afh[((kstep * 4 + wave) * 64 + lane) * 8];
        short8 ah = *(const short8*)af;
        short8 al = *(const short8*)(af + (Afl - Afh));
        const ushort* bph = &Bsh[kstep * 4096 + lane * 8];
        const ushort* bpl = &Bsl[kstep * 4096 + lane * 8];
#pragma unroll
        for (int nt = 0; nt < 8; ++nt) {
          short8 bh = *(const short8*)(bph + nt * 512);
          short8 bl = *(const short8*)(bpl + nt * 512);
          acc[hf][nt] = __builtin_amdgcn_mfma_f32_16x16x32_bf16(al, bh, acc[hf][nt], 0, 0, 0);
          acc[hf][nt] = __builtin_amdgcn_mfma_f32_16x16x32_bf16(ah, bl, acc[hf][nt], 0, 0, 0);
          acc[hf][nt] = __builtin_amdgcn_mfma_f32_16x16x32_bf16(ah, bh, acc[hf][nt], 0, 0, 0);
        }
      }
      __syncthreads();  // allow A overwrite (hf=0) / next-bk B overwrite (hf=1)
    }
  }
  float* pb = preact + (size_t)ks * kB * kH;
#pragma unroll
  for (int hf = 0; hf < 2; ++hf)
#pragma unroll
    for (int r = 0; r < 4; ++r) {
      int row = hf * 64 + wave * 16 + kg4 * 4 + r;
      if (row < M) {
        float* pr = pb + (size_t)rows[row] * kH + m15;
#pragma unroll
        for (int nt = 0; nt < 8; ++nt) pr[nt * 16] = acc[hf][nt][r];
      }
    }
}

// Per-token tail. R20: 4 tokens per 256-thread block (one wave per token,
// body verbatim -> bit-identical); 4096 -> 1024 blocks cuts launch/drain.
__global__ __launch_bounds__(256) void expert_tail(
    const float* __restrict__ preact, const float* __restrict__ b1,
    const float* __restrict__ w2, const float* __restrict__ b2,
    const int* __restrict__ idx, const float* __restrict__ scale,
    float* __restrict__ out) {
  const int b = blockIdx.x * 4 + (threadIdx.x >> 6);
  const int lane = threadIdx.x & 63;
  const int e = idx[b];
  float pa = 0.f, pc = 0.f;
#pragma unroll
  for (int ks = 0; ks < KSPLIT; ++ks) {
    const float* ps = preact + ((size_t)ks * kB + b) * kH;
    pa += ps[lane];
    pc += ps[64 + lane];
  }
  float hea = fmaxf(pa + b1[e * kH + lane], 0.f);
  float heb = fmaxf(pc + b1[e * kH + 64 + lane], 0.f);
  const float* w2a = w2 + ((size_t)e * kH + lane) * kO;
  const float* w2b = w2a + 64 * kO;
  float part[kO];
#pragma unroll
  for (int o = 0; o < kO; ++o) part[o] = hea * w2a[o] + heb * w2b[o];
#pragma unroll
  for (int off = 32; off > 0; off >>= 1)
#pragma unroll
    for (int o = 0; o < kO; ++o) part[o] += __shfl_down(part[o], off, 64);
  if (lane == 0) {
    const float sc = scale[b];
    float v[kO], m = -1e30f;
#pragma unroll
    for (int o = 0; o < kO; ++o) {
      v[o] = (part[o] + b2[e * kO + o]) * sc;
      m = fmaxf(m, v[o]);
    }
    float s = 0.f;
#pragma unroll
    for (int o = 0; o < kO; ++o) s += expf(v[o] - m);
    const float lse = m + logf(s);
#pragma unroll
    for (int o = 0; o < kO; ++o) out[(size_t)b * kO + o] = v[o] - lse;
  }
}

}  // namespace

extern "C" void kernel_launch(void* const* d_in, const int* in_sizes, int n_in,
                              void* d_out, int out_size, void* d_ws,
                              size_t ws_size, hipStream_t stream) {
  (void)in_sizes; (void)n_in; (void)out_size; (void)ws_size;
  const float* x   = (const float*)d_in[0];
  const float* c1w = (const float*)d_in[1];
  const float* c1b = (const float*)d_in[2];
  const float* c2w = (const float*)d_in[3];
  const float* c2b = (const float*)d_in[4];
  const float* gw  = (const float*)d_in[5];
  const float* w1  = (const float*)d_in[6];
  const float* b1  = (const float*)d_in[7];
  const float* w2  = (const float*)d_in[8];
  const float* b2  = (const float*)d_in[9];
  float* out = (float*)d_out;

  char* ws = (char*)d_ws;
  float* h = (float*)ws;
  size_t off = (size_t)kB * kD * sizeof(float);                     // 151.0 MB
  ushort* w1ph = (ushort*)(ws + off); off += (size_t)kE * kD * kH * 2;  // 18.9 MB
  ushort* w1pl = (ushort*)(ws + off); off += (size_t)kE * kD * kH * 2;  // 18.9 MB
  float* preact = (float*)(ws + off); off += (size_t)KSPLIT * kB * kH * 4;  // 16.8 MB
  ushort* Bph = (ushort*)(ws + off);  off += 9 * 4 * 64 * 8 * 2;
  ushort* Bpl = (ushort*)(ws + off);  off += 9 * 4 * 64 * 8 * 2;
  int* idx = (int*)(ws + off);        off += (size_t)kB * 4;
  float* scale = (float*)(ws + off);  off += (size_t)kB * 4;
  int* perm = (int*)(ws + off);       off += (size_t)kB * 4;
  int* counts = (int*)(ws + off);     off += 64;   // [0..7]=counts, [8..15]=gcur
  int* offsets = (int*)(ws + off);    off += 64;

  prep_w1<<<4608, 256, 0, stream>>>(w1, w1ph, w1pl, c2w, Bph, Bpl, counts);
  conv_kernel<<<kB, 256, 0, stream>>>(x, c1w, c1b, c2b, Bph, Bpl, gw, h,
                                      idx, scale, counts);
  scatter_kernel<<<kB / 256, 256, 0, stream>>>(counts, idx, offsets, perm,
                                               counts + kE);
  dim3 eg(kE, KSPLIT, 8);
  expert_gemm<<<eg, 256, 0, stream>>>(h, w1ph, w1pl, perm, offsets, preact);
  expert_tail<<<kB / 4, 256, 0, stream>>>(preact, b1, w2, b2, idx, scale, out);
}